// Round 4
// baseline (554.498 us; speedup 1.0000x reference)
//
#include <hip/hip_runtime.h>
#include <hip/hip_bf16.h>

// MLA forward, MI355X. B=2, S=2048, DIM=2048, H=16, QK_HD=192 (128 nope + 64 rope), V_HD=128.
// R3: attention gets a 2-phase reg-staged prefetch pipeline (T14), paired-k b32 V-staging
// (4-way -> 2-way banks), setprio around MFMA clusters. GEMMs unchanged (R2 structure).

typedef __attribute__((ext_vector_type(8))) short short8;
typedef __attribute__((ext_vector_type(4))) short short4v;
typedef __attribute__((ext_vector_type(4))) float f32x4;

#define GLOAD_LDS16(gp, lp)                                                      \
  __builtin_amdgcn_global_load_lds((const __attribute__((address_space(1))) void*)(gp), \
                                   (__attribute__((address_space(3))) void*)(lp), 16, 0, 0)

static __device__ __forceinline__ unsigned short bf16_bits(float f) {
  __hip_bfloat16 h = __float2bfloat16(f);
  return __builtin_bit_cast(unsigned short, h);
}
static __device__ __forceinline__ float bf16_to_f(unsigned short u) {
  unsigned int v = (unsigned int)u << 16;
  return __builtin_bit_cast(float, v);
}

// ---------------- conversion kernels ----------------

__global__ void k_f32_to_bf16(const float* __restrict__ in, unsigned short* __restrict__ out, int n4) {
  int i = blockIdx.x * 256 + threadIdx.x;
  if (i >= n4) return;
  float4 v = reinterpret_cast<const float4*>(in)[i];
  ushort4 o;
  o.x = bf16_bits(v.x); o.y = bf16_bits(v.y); o.z = bf16_bits(v.z); o.w = bf16_bits(v.w);
  reinterpret_cast<ushort4*>(out)[i] = o;
}

// W[K][N] fp32 -> Wt[N][K] bf16 (LDS-tiled transpose)
__global__ void k_transpose_bf16(const float* __restrict__ W, unsigned short* __restrict__ Wt,
                                 int K, int N) {
  __shared__ float tile[32][33];
  int k0 = blockIdx.x * 32, n0 = blockIdx.y * 32;
  int tx = threadIdx.x & 31, ty = threadIdx.x >> 5;  // ty 0..7
#pragma unroll
  for (int i = 0; i < 32; i += 8) {
    int k = k0 + ty + i, n = n0 + tx;
    tile[ty + i][tx] = (k < K && n < N) ? W[(size_t)k * N + n] : 0.f;
  }
  __syncthreads();
#pragma unroll
  for (int i = 0; i < 32; i += 8) {
    int n = n0 + ty + i, k = k0 + tx;
    if (n < N && k < K) Wt[(size_t)n * K + k] = bf16_bits(tile[tx][ty + i]);
  }
}

// ---------------- RoPE ----------------

__global__ void k_rope_table(float2* __restrict__ cs) {
  int idx = blockIdx.x * 256 + threadIdx.x;  // 2048*32 total
  int s = idx >> 5, i = idx & 31;
  float inv = powf(1.0e6f, -(float)(2 * i) / 64.0f);
  float a = (float)s * inv;
  cs[idx] = make_float2(cosf(a), sinf(a));
}

__global__ void k_rope_q(unsigned short* __restrict__ q, const float2* __restrict__ cs) {
  int idx = blockIdx.x * 256 + threadIdx.x;  // BS*16*32
  int i = idx & 31;
  int h = (idx >> 5) & 15;
  int bs = idx >> 9;
  int s = bs & 2047;
  size_t base = (size_t)bs * 3072 + h * 192 + 128 + 2 * i;
  float xr = bf16_to_f(q[base]);
  float xi = bf16_to_f(q[base + 1]);
  float2 c = cs[(s << 5) + i];
  q[base]     = bf16_bits(xr * c.x - xi * c.y);
  q[base + 1] = bf16_bits(xr * c.y + xi * c.x);
}

__global__ void k_rope_k(unsigned short* __restrict__ ckv, const float2* __restrict__ cs) {
  int idx = blockIdx.x * 256 + threadIdx.x;  // BS*32
  int i = idx & 31;
  int bs = idx >> 5;
  int s = bs & 2047;
  size_t base = (size_t)bs * 576 + 512 + 2 * i;
  float xr = bf16_to_f(ckv[base]);
  float xi = bf16_to_f(ckv[base + 1]);
  float2 c = cs[(s << 5) + i];
  ckv[base]     = bf16_bits(xr * c.x - xi * c.y);
  ckv[base + 1] = bf16_bits(xr * c.y + xi * c.x);
}

// ---------------- GEMM: C[M][N] = A[M][K](lda) @ Wt[N][K]^T + bias ----------------
// (unchanged R2 structure: global_load_lds w16, linear LDS + pre-swizzled source)

template <typename OutT>
__global__ __launch_bounds__(256, 2) void k_gemm(const unsigned short* __restrict__ A, int lda,
                                                 const unsigned short* __restrict__ Wt,
                                                 const float* __restrict__ bias,
                                                 OutT* __restrict__ C, int M, int N, int K) {
  __shared__ unsigned short lA[128][64];
  __shared__ unsigned short lB[128][64];
  int m0 = blockIdx.x * 128, n0 = blockIdx.y * 128;
  int t = threadIdx.x;
  int lane = t & 63, wid = t >> 6;
  int g = lane >> 4, col = lane & 15;
  int wr = wid >> 1, wc = wid & 1;
  int srow = lane >> 3;                 // 0..7 within wave chunk
  int schunk = (lane & 7) ^ srow;       // inverse-swizzled source chunk
  f32x4 acc[4][4] = {};

  for (int kt = 0; kt < K; kt += 64) {
#pragma unroll
    for (int i = 0; i < 4; ++i) {
      int rowb = 32 * wid + 8 * i;      // wave-uniform LDS row base
      int row = rowb + srow;
      GLOAD_LDS16(&A[(size_t)(m0 + row) * lda + kt + 8 * schunk], &lA[rowb][0]);
      GLOAD_LDS16(&Wt[(size_t)(n0 + row) * K + kt + 8 * schunk], &lB[rowb][0]);
    }
    __syncthreads();
#pragma unroll
    for (int kk = 0; kk < 64; kk += 32) {
      int ch = (kk >> 3) + g;
      int sl = 8 * (ch ^ (col & 7));
      short8 a[4], b[4];
#pragma unroll
      for (int mf = 0; mf < 4; ++mf)
        a[mf] = *reinterpret_cast<const short8*>(&lA[64 * wr + 16 * mf + col][sl]);
#pragma unroll
      for (int nf = 0; nf < 4; ++nf)
        b[nf] = *reinterpret_cast<const short8*>(&lB[64 * wc + 16 * nf + col][sl]);
#pragma unroll
      for (int mf = 0; mf < 4; ++mf)
#pragma unroll
        for (int nf = 0; nf < 4; ++nf)
          acc[mf][nf] = __builtin_amdgcn_mfma_f32_16x16x32_bf16(a[mf], b[nf], acc[mf][nf], 0, 0, 0);
    }
    __syncthreads();
  }

#pragma unroll
  for (int mf = 0; mf < 4; ++mf) {
#pragma unroll
    for (int nf = 0; nf < 4; ++nf) {
      int n = n0 + 64 * wc + 16 * nf + col;
      if (n >= N) continue;
      float bv = bias[n];
#pragma unroll
      for (int r = 0; r < 4; ++r) {
        int m = m0 + 64 * wr + 16 * mf + 4 * g + r;
        float v = acc[mf][nf][r] + bv;
        if constexpr (sizeof(OutT) == 4)
          C[(size_t)m * N + n] = v;
        else
          C[(size_t)m * N + n] = bf16_bits(v);
      }
    }
  }
}

// ---------------- flash attention (R3) ----------------
// grid = B*H*(S/128) = 512 blocks, 512 threads = 8 waves; wave w owns q-rows [q0+16w, +16).
// 2-phase pipeline: tile t staged to regs during tile t-1 compute; per tile:
// barrier -> ds_write regs -> barrier -> issue loads(t+1) -> sched_barrier -> compute.
// V^T layout: element V[k][dv] at lV[dv][ ((k>>3)^((dv>>3)&7))*8 + (k&7) ].
// V staged as k-pairs: per unit, 2 x b64 global loads, 4 x b32 LDS writes (2-way banks).

__global__ __launch_bounds__(512, 4) void k_attn(const unsigned short* __restrict__ q,
                                                 const unsigned short* __restrict__ ckv,
                                                 const unsigned short* __restrict__ kv,
                                                 unsigned short* __restrict__ out) {
  __shared__ unsigned short lK[64][200];    // 64 kv-rows x 192 dims (+8 pad)
  __shared__ unsigned short lV[128][72];    // V^T swizzled: 128 dv x 64 kv (+8 pad)
  __shared__ unsigned short lP[8][16][72];  // per-wave P 16x64 (+8 pad), wave-private
  int bx = blockIdx.x;
  int qt = bx & 15, h = (bx >> 4) & 15, b = bx >> 8;
  int t = threadIdx.x, lane = t & 63, w = t >> 6;
  int g = lane >> 4, col = lane & 15;
  int q0 = qt * 128;
  int bb = b * 2048;
  const float scale = 0.08838834764831845f;  // 1/sqrt(128)

  short8 qf[6];
  {
    int srow = bb + q0 + 16 * w + col;
    size_t base = ((size_t)srow * 16 + h) * 192 + 8 * g;
#pragma unroll
    for (int j = 0; j < 6; ++j)
      qf[j] = *reinterpret_cast<const short8*>(&q[base + 32 * j]);
  }

  // staging registers
  short8 kreg[3];
  short4v vreg0[2], vreg1[2];

  auto load_tile = [&](int k0) {
#pragma unroll
    for (int it = 0; it < 3; ++it) {
      int c = t + 512 * it;
      int row = c / 24, cc = c % 24;
      int s = bb + k0 + row;
      const unsigned short* src;
      if (cc < 16) src = &kv[((size_t)s * 16 + h) * 256 + cc * 8];
      else         src = &ckv[(size_t)s * 576 + 512 + (cc - 16) * 8];
      kreg[it] = *reinterpret_cast<const short8*>(src);
    }
#pragma unroll
    for (int it = 0; it < 2; ++it) {
      int c = t + 512 * it;
      int kp = c >> 5, dv0 = (c & 31) * 4;
      size_t vb = ((size_t)(bb + k0 + 2 * kp) * 16 + h) * 256 + 128 + dv0;
      vreg0[it] = *reinterpret_cast<const short4v*>(&kv[vb]);
      vreg1[it] = *reinterpret_cast<const short4v*>(&kv[vb + 4096]);  // next kv row
    }
  };

  load_tile(0);

  f32x4 o[8] = {};
  float mrow[4] = {-1e30f, -1e30f, -1e30f, -1e30f};
  float lrow[4] = {0.f, 0.f, 0.f, 0.f};

  for (int k0 = 0; k0 < 2048; k0 += 64) {
    __syncthreads();  // prior tile's LDS reads complete
    // ---- write staged regs -> LDS ----
#pragma unroll
    for (int it = 0; it < 3; ++it) {
      int c = t + 512 * it;
      int row = c / 24, cc = c % 24;
      *reinterpret_cast<short8*>(&lK[row][cc * 8]) = kreg[it];
    }
#pragma unroll
    for (int it = 0; it < 2; ++it) {
      int c = t + 512 * it;
      int kp = c >> 5, dv0 = (c & 31) * 4;
      int k2 = 2 * kp;
#pragma unroll
      for (int j = 0; j < 4; ++j) {
        int dv = dv0 + j;
        int phys = (((k2 >> 3) ^ ((dv >> 3) & 7)) << 3) + (k2 & 7);
        unsigned int pw = (unsigned int)(unsigned short)vreg0[it][j] |
                          ((unsigned int)(unsigned short)vreg1[it][j] << 16);
        *reinterpret_cast<unsigned int*>(&lV[dv][phys]) = pw;
      }
    }
    __syncthreads();
    // ---- issue next tile's global loads (hidden under compute) ----
    if (k0 + 64 < 2048) load_tile(k0 + 64);
    __builtin_amdgcn_sched_barrier(0);  // keep loads issued before compute

    // ---- S = Q K^T for this wave's 16 rows x 64 cols ----
    f32x4 sf[4];
    __builtin_amdgcn_s_setprio(1);
#pragma unroll
    for (int c = 0; c < 4; ++c) {
      f32x4 acc = {};
#pragma unroll
      for (int j = 0; j < 6; ++j) {
        short8 bfr = *reinterpret_cast<const short8*>(&lK[16 * c + col][32 * j + 8 * g]);
        acc = __builtin_amdgcn_mfma_f32_16x16x32_bf16(qf[j], bfr, acc, 0, 0, 0);
      }
      sf[c] = acc;
    }
    __builtin_amdgcn_s_setprio(0);

    // ---- online softmax; row r of this lane = q0+16w+4g+r ----
#pragma unroll
    for (int r = 0; r < 4; ++r) {
      float tm = -1e30f;
#pragma unroll
      for (int c = 0; c < 4; ++c) { sf[c][r] *= scale; tm = fmaxf(tm, sf[c][r]); }
#pragma unroll
      for (int off = 8; off; off >>= 1) tm = fmaxf(tm, __shfl_xor(tm, off, 64));
      float mn = fmaxf(mrow[r], tm);
      float rs = __expf(mrow[r] - mn);
      mrow[r] = mn;
      float ps = 0.f;
#pragma unroll
      for (int c = 0; c < 4; ++c) { float p = __expf(sf[c][r] - mn); sf[c][r] = p; ps += p; }
#pragma unroll
      for (int off = 8; off; off >>= 1) ps += __shfl_xor(ps, off, 64);
      lrow[r] = lrow[r] * rs + ps;
#pragma unroll
      for (int n = 0; n < 8; ++n) o[n][r] *= rs;
    }

    // ---- P -> wave-private LDS (bf16); same-wave DS ops in-order, no block barrier ----
#pragma unroll
    for (int c = 0; c < 4; ++c)
#pragma unroll
      for (int r = 0; r < 4; ++r)
        lP[w][4 * g + r][16 * c + col] = bf16_bits(sf[c][r]);
    __builtin_amdgcn_s_setprio(1);
#pragma unroll
    for (int kk = 0; kk < 64; kk += 32) {
      short8 pa = *reinterpret_cast<const short8*>(&lP[w][col][kk + 8 * g]);
#pragma unroll
      for (int n = 0; n < 8; ++n) {
        int dv = 16 * n + col;
        int phys = ((((kk + 8 * g) >> 3) ^ ((dv >> 3) & 7)) << 3);
        short8 bv = *reinterpret_cast<const short8*>(&lV[dv][phys]);
        o[n] = __builtin_amdgcn_mfma_f32_16x16x32_bf16(pa, bv, o[n], 0, 0, 0);
      }
    }
    __builtin_amdgcn_s_setprio(0);
  }

  // epilogue: normalize, write (B,S,H*128) bf16
#pragma unroll
  for (int r = 0; r < 4; ++r) {
    float inv = 1.0f / lrow[r];
    int srow = bb + q0 + 16 * w + 4 * g + r;
    size_t base = (size_t)srow * 2048 + h * 128;
#pragma unroll
    for (int n = 0; n < 8; ++n)
      out[base + 16 * n + col] = bf16_bits(o[n][r] * inv);
  }
}

// ---------------- host ----------------

extern "C" void kernel_launch(void* const* d_in, const int* in_sizes, int n_in,
                              void* d_out, int out_size, void* d_ws, size_t ws_size,
                              hipStream_t stream) {
  const float* x       = (const float*)d_in[0];
  const float* wq_a_w  = (const float*)d_in[1];
  const float* wq_a_b  = (const float*)d_in[2];
  const float* wq_b_w  = (const float*)d_in[3];
  const float* wq_b_b  = (const float*)d_in[4];
  const float* wkv_a_w = (const float*)d_in[5];
  const float* wkv_a_b = (const float*)d_in[6];
  const float* wkv_b_w = (const float*)d_in[7];
  const float* wkv_b_b = (const float*)d_in[8];
  const float* wo_w    = (const float*)d_in[9];
  const float* wo_b    = (const float*)d_in[10];
  float* out = (float*)d_out;

  const int BS = 4096;  // B*S = 2*2048
  char* p = (char*)d_ws;
  auto alloc = [&](size_t bytes) { char* r = p; p += (bytes + 255) & ~(size_t)255; return r; };
  unsigned short* xb    = (unsigned short*)alloc((size_t)BS * 2048 * 2);
  unsigned short* wqat  = (unsigned short*)alloc((size_t)512 * 2048 * 2);
  unsigned short* wqbt  = (unsigned short*)alloc((size_t)3072 * 512 * 2);
  unsigned short* wkvat = (unsigned short*)alloc((size_t)640 * 2048 * 2);  // padded 576->640
  unsigned short* wkvbt = (unsigned short*)alloc((size_t)4096 * 512 * 2);
  unsigned short* wot   = (unsigned short*)alloc((size_t)2048 * 2048 * 2);
  unsigned short* qa    = (unsigned short*)alloc((size_t)BS * 512 * 2);
  unsigned short* qbuf  = (unsigned short*)alloc((size_t)BS * 3072 * 2);
  unsigned short* ckv   = (unsigned short*)alloc((size_t)BS * 576 * 2);
  unsigned short* kvbuf = (unsigned short*)alloc((size_t)BS * 4096 * 2);
  unsigned short* attno = (unsigned short*)alloc((size_t)BS * 2048 * 2);
  float2* cs            = (float2*)alloc((size_t)2048 * 32 * sizeof(float2));

  k_f32_to_bf16<<<BS * 2048 / 4 / 256, 256, 0, stream>>>(x, xb, BS * 2048 / 4);
  k_transpose_bf16<<<dim3(2048 / 32, 512 / 32), 256, 0, stream>>>(wq_a_w, wqat, 2048, 512);
  k_transpose_bf16<<<dim3(512 / 32, 3072 / 32), 256, 0, stream>>>(wq_b_w, wqbt, 512, 3072);
  k_transpose_bf16<<<dim3(2048 / 32, 576 / 32), 256, 0, stream>>>(wkv_a_w, wkvat, 2048, 576);
  k_transpose_bf16<<<dim3(512 / 32, 4096 / 32), 256, 0, stream>>>(wkv_b_w, wkvbt, 512, 4096);
  k_transpose_bf16<<<dim3(2048 / 32, 2048 / 32), 256, 0, stream>>>(wo_w, wot, 2048, 2048);
  k_rope_table<<<2048 * 32 / 256, 256, 0, stream>>>(cs);

  // GEMM1: q_a = x @ wq_a + b
  k_gemm<unsigned short><<<dim3(BS / 128, 512 / 128), 256, 0, stream>>>(
      xb, 2048, wqat, wq_a_b, qa, BS, 512, 2048);
  // GEMM2: q = q_a @ wq_b + b
  k_gemm<unsigned short><<<dim3(BS / 128, 3072 / 128), 256, 0, stream>>>(
      qa, 512, wqbt, wq_b_b, qbuf, BS, 3072, 512);
  // GEMM3: ckv = x @ wkv_a + b
  k_gemm<unsigned short><<<dim3(BS / 128, (576 + 127) / 128), 256, 0, stream>>>(
      xb, 2048, wkvat, wkv_a_b, ckv, BS, 576, 2048);
  // RoPE in place
  k_rope_q<<<BS * 16 * 32 / 256, 256, 0, stream>>>(qbuf, cs);
  k_rope_k<<<BS * 32 / 256, 256, 0, stream>>>(ckv, cs);
  // GEMM4: kv = compressed_kv @ wkv_b + b
  k_gemm<unsigned short><<<dim3(BS / 128, 4096 / 128), 256, 0, stream>>>(
      ckv, 576, wkvbt, wkv_b_b, kvbuf, BS, 4096, 512);
  // attention: 512 blocks x 512 threads
  k_attn<<<2 * 16 * 16, 512, 0, stream>>>(qbuf, ckv, kvbuf, attno);
  // GEMM5: final projection, fp32 out
  k_gemm<float><<<dim3(BS / 128, 2048 / 128), 256, 0, stream>>>(
      attno, 2048, wot, wo_b, out, BS, 2048, 2048);
}

// Round 5
// 501.858 us; speedup vs baseline: 1.1049x; 1.1049x over previous
//
#include <hip/hip_runtime.h>
#include <hip/hip_bf16.h>

// MLA forward, MI355X. B=2, S=2048, DIM=2048, H=16, QK_HD=192 (128 nope + 64 rope), V_HD=128.
// R4: k_attn __launch_bounds__(512,4) -> (512,2). The (512,4) bound capped VGPRs at 64
// (8 waves/SIMD target) while LDS already capped occupancy at 2 blocks/CU -> R3's
// reg-staging spilled to scratch (FETCH +100MB). 128-VGPR budget removes the spill.

typedef __attribute__((ext_vector_type(8))) short short8;
typedef __attribute__((ext_vector_type(4))) short short4v;
typedef __attribute__((ext_vector_type(4))) float f32x4;

#define GLOAD_LDS16(gp, lp)                                                      \
  __builtin_amdgcn_global_load_lds((const __attribute__((address_space(1))) void*)(gp), \
                                   (__attribute__((address_space(3))) void*)(lp), 16, 0, 0)

static __device__ __forceinline__ unsigned short bf16_bits(float f) {
  __hip_bfloat16 h = __float2bfloat16(f);
  return __builtin_bit_cast(unsigned short, h);
}
static __device__ __forceinline__ float bf16_to_f(unsigned short u) {
  unsigned int v = (unsigned int)u << 16;
  return __builtin_bit_cast(float, v);
}

// ---------------- conversion kernels ----------------

__global__ void k_f32_to_bf16(const float* __restrict__ in, unsigned short* __restrict__ out, int n4) {
  int i = blockIdx.x * 256 + threadIdx.x;
  if (i >= n4) return;
  float4 v = reinterpret_cast<const float4*>(in)[i];
  ushort4 o;
  o.x = bf16_bits(v.x); o.y = bf16_bits(v.y); o.z = bf16_bits(v.z); o.w = bf16_bits(v.w);
  reinterpret_cast<ushort4*>(out)[i] = o;
}

// W[K][N] fp32 -> Wt[N][K] bf16 (LDS-tiled transpose)
__global__ void k_transpose_bf16(const float* __restrict__ W, unsigned short* __restrict__ Wt,
                                 int K, int N) {
  __shared__ float tile[32][33];
  int k0 = blockIdx.x * 32, n0 = blockIdx.y * 32;
  int tx = threadIdx.x & 31, ty = threadIdx.x >> 5;  // ty 0..7
#pragma unroll
  for (int i = 0; i < 32; i += 8) {
    int k = k0 + ty + i, n = n0 + tx;
    tile[ty + i][tx] = (k < K && n < N) ? W[(size_t)k * N + n] : 0.f;
  }
  __syncthreads();
#pragma unroll
  for (int i = 0; i < 32; i += 8) {
    int n = n0 + ty + i, k = k0 + tx;
    if (n < N && k < K) Wt[(size_t)n * K + k] = bf16_bits(tile[tx][ty + i]);
  }
}

// ---------------- RoPE ----------------

__global__ void k_rope_table(float2* __restrict__ cs) {
  int idx = blockIdx.x * 256 + threadIdx.x;  // 2048*32 total
  int s = idx >> 5, i = idx & 31;
  float inv = powf(1.0e6f, -(float)(2 * i) / 64.0f);
  float a = (float)s * inv;
  cs[idx] = make_float2(cosf(a), sinf(a));
}

__global__ void k_rope_q(unsigned short* __restrict__ q, const float2* __restrict__ cs) {
  int idx = blockIdx.x * 256 + threadIdx.x;  // BS*16*32
  int i = idx & 31;
  int h = (idx >> 5) & 15;
  int bs = idx >> 9;
  int s = bs & 2047;
  size_t base = (size_t)bs * 3072 + h * 192 + 128 + 2 * i;
  float xr = bf16_to_f(q[base]);
  float xi = bf16_to_f(q[base + 1]);
  float2 c = cs[(s << 5) + i];
  q[base]     = bf16_bits(xr * c.x - xi * c.y);
  q[base + 1] = bf16_bits(xr * c.y + xi * c.x);
}

__global__ void k_rope_k(unsigned short* __restrict__ ckv, const float2* __restrict__ cs) {
  int idx = blockIdx.x * 256 + threadIdx.x;  // BS*32
  int i = idx & 31;
  int bs = idx >> 5;
  int s = bs & 2047;
  size_t base = (size_t)bs * 576 + 512 + 2 * i;
  float xr = bf16_to_f(ckv[base]);
  float xi = bf16_to_f(ckv[base + 1]);
  float2 c = cs[(s << 5) + i];
  ckv[base]     = bf16_bits(xr * c.x - xi * c.y);
  ckv[base + 1] = bf16_bits(xr * c.y + xi * c.x);
}

// ---------------- GEMM: C[M][N] = A[M][K](lda) @ Wt[N][K]^T + bias ----------------
// (unchanged R2 structure: global_load_lds w16, linear LDS + pre-swizzled source)

template <typename OutT>
__global__ __launch_bounds__(256, 2) void k_gemm(const unsigned short* __restrict__ A, int lda,
                                                 const unsigned short* __restrict__ Wt,
                                                 const float* __restrict__ bias,
                                                 OutT* __restrict__ C, int M, int N, int K) {
  __shared__ unsigned short lA[128][64];
  __shared__ unsigned short lB[128][64];
  int m0 = blockIdx.x * 128, n0 = blockIdx.y * 128;
  int t = threadIdx.x;
  int lane = t & 63, wid = t >> 6;
  int g = lane >> 4, col = lane & 15;
  int wr = wid >> 1, wc = wid & 1;
  int srow = lane >> 3;                 // 0..7 within wave chunk
  int schunk = (lane & 7) ^ srow;       // inverse-swizzled source chunk
  f32x4 acc[4][4] = {};

  for (int kt = 0; kt < K; kt += 64) {
#pragma unroll
    for (int i = 0; i < 4; ++i) {
      int rowb = 32 * wid + 8 * i;      // wave-uniform LDS row base
      int row = rowb + srow;
      GLOAD_LDS16(&A[(size_t)(m0 + row) * lda + kt + 8 * schunk], &lA[rowb][0]);
      GLOAD_LDS16(&Wt[(size_t)(n0 + row) * K + kt + 8 * schunk], &lB[rowb][0]);
    }
    __syncthreads();
#pragma unroll
    for (int kk = 0; kk < 64; kk += 32) {
      int ch = (kk >> 3) + g;
      int sl = 8 * (ch ^ (col & 7));
      short8 a[4], b[4];
#pragma unroll
      for (int mf = 0; mf < 4; ++mf)
        a[mf] = *reinterpret_cast<const short8*>(&lA[64 * wr + 16 * mf + col][sl]);
#pragma unroll
      for (int nf = 0; nf < 4; ++nf)
        b[nf] = *reinterpret_cast<const short8*>(&lB[64 * wc + 16 * nf + col][sl]);
#pragma unroll
      for (int mf = 0; mf < 4; ++mf)
#pragma unroll
        for (int nf = 0; nf < 4; ++nf)
          acc[mf][nf] = __builtin_amdgcn_mfma_f32_16x16x32_bf16(a[mf], b[nf], acc[mf][nf], 0, 0, 0);
    }
    __syncthreads();
  }

#pragma unroll
  for (int mf = 0; mf < 4; ++mf) {
#pragma unroll
    for (int nf = 0; nf < 4; ++nf) {
      int n = n0 + 64 * wc + 16 * nf + col;
      if (n >= N) continue;
      float bv = bias[n];
#pragma unroll
      for (int r = 0; r < 4; ++r) {
        int m = m0 + 64 * wr + 16 * mf + 4 * g + r;
        float v = acc[mf][nf][r] + bv;
        if constexpr (sizeof(OutT) == 4)
          C[(size_t)m * N + n] = v;
        else
          C[(size_t)m * N + n] = bf16_bits(v);
      }
    }
  }
}

// ---------------- flash attention (R4) ----------------
// grid = B*H*(S/128) = 512 blocks, 512 threads = 8 waves; wave w owns q-rows [q0+16w, +16).
// 2-phase reg-staged pipeline; launch_bounds (512,2): LDS caps occupancy at 2 blocks/CU
// anyway, so take the 128-VGPR budget (the (512,4) 64-VGPR cap caused scratch spill, R3).

__global__ __launch_bounds__(512, 2) void k_attn(const unsigned short* __restrict__ q,
                                                 const unsigned short* __restrict__ ckv,
                                                 const unsigned short* __restrict__ kv,
                                                 unsigned short* __restrict__ out) {
  __shared__ unsigned short lK[64][200];    // 64 kv-rows x 192 dims (+8 pad)
  __shared__ unsigned short lV[128][72];    // V^T swizzled: 128 dv x 64 kv (+8 pad)
  __shared__ unsigned short lP[8][16][72];  // per-wave P 16x64 (+8 pad), wave-private
  int bx = blockIdx.x;
  int qt = bx & 15, h = (bx >> 4) & 15, b = bx >> 8;
  int t = threadIdx.x, lane = t & 63, w = t >> 6;
  int g = lane >> 4, col = lane & 15;
  int q0 = qt * 128;
  int bb = b * 2048;
  const float scale = 0.08838834764831845f;  // 1/sqrt(128)

  short8 qf[6];
  {
    int srow = bb + q0 + 16 * w + col;
    size_t base = ((size_t)srow * 16 + h) * 192 + 8 * g;
#pragma unroll
    for (int j = 0; j < 6; ++j)
      qf[j] = *reinterpret_cast<const short8*>(&q[base + 32 * j]);
  }

  // staging registers
  short8 kreg[3];
  short4v vreg0[2], vreg1[2];

  auto load_tile = [&](int k0) {
#pragma unroll
    for (int it = 0; it < 3; ++it) {
      int c = t + 512 * it;
      int row = c / 24, cc = c % 24;
      int s = bb + k0 + row;
      const unsigned short* src;
      if (cc < 16) src = &kv[((size_t)s * 16 + h) * 256 + cc * 8];
      else         src = &ckv[(size_t)s * 576 + 512 + (cc - 16) * 8];
      kreg[it] = *reinterpret_cast<const short8*>(src);
    }
#pragma unroll
    for (int it = 0; it < 2; ++it) {
      int c = t + 512 * it;
      int kp = c >> 5, dv0 = (c & 31) * 4;
      size_t vb = ((size_t)(bb + k0 + 2 * kp) * 16 + h) * 256 + 128 + dv0;
      vreg0[it] = *reinterpret_cast<const short4v*>(&kv[vb]);
      vreg1[it] = *reinterpret_cast<const short4v*>(&kv[vb + 4096]);  // next kv row
    }
  };

  load_tile(0);

  f32x4 o[8] = {};
  float mrow[4] = {-1e30f, -1e30f, -1e30f, -1e30f};
  float lrow[4] = {0.f, 0.f, 0.f, 0.f};

  for (int k0 = 0; k0 < 2048; k0 += 64) {
    __syncthreads();  // prior tile's LDS reads complete
    // ---- write staged regs -> LDS ----
#pragma unroll
    for (int it = 0; it < 3; ++it) {
      int c = t + 512 * it;
      int row = c / 24, cc = c % 24;
      *reinterpret_cast<short8*>(&lK[row][cc * 8]) = kreg[it];
    }
#pragma unroll
    for (int it = 0; it < 2; ++it) {
      int c = t + 512 * it;
      int kp = c >> 5, dv0 = (c & 31) * 4;
      int k2 = 2 * kp;
#pragma unroll
      for (int j = 0; j < 4; ++j) {
        int dv = dv0 + j;
        int phys = (((k2 >> 3) ^ ((dv >> 3) & 7)) << 3) + (k2 & 7);
        unsigned int pw = (unsigned int)(unsigned short)vreg0[it][j] |
                          ((unsigned int)(unsigned short)vreg1[it][j] << 16);
        *reinterpret_cast<unsigned int*>(&lV[dv][phys]) = pw;
      }
    }
    __syncthreads();
    // ---- issue next tile's global loads (hidden under compute) ----
    if (k0 + 64 < 2048) load_tile(k0 + 64);
    __builtin_amdgcn_sched_barrier(0);  // keep loads issued before compute

    // ---- S = Q K^T for this wave's 16 rows x 64 cols ----
    f32x4 sf[4];
    __builtin_amdgcn_s_setprio(1);
#pragma unroll
    for (int c = 0; c < 4; ++c) {
      f32x4 acc = {};
#pragma unroll
      for (int j = 0; j < 6; ++j) {
        short8 bfr = *reinterpret_cast<const short8*>(&lK[16 * c + col][32 * j + 8 * g]);
        acc = __builtin_amdgcn_mfma_f32_16x16x32_bf16(qf[j], bfr, acc, 0, 0, 0);
      }
      sf[c] = acc;
    }
    __builtin_amdgcn_s_setprio(0);

    // ---- online softmax; row r of this lane = q0+16w+4g+r ----
#pragma unroll
    for (int r = 0; r < 4; ++r) {
      float tm = -1e30f;
#pragma unroll
      for (int c = 0; c < 4; ++c) { sf[c][r] *= scale; tm = fmaxf(tm, sf[c][r]); }
#pragma unroll
      for (int off = 8; off; off >>= 1) tm = fmaxf(tm, __shfl_xor(tm, off, 64));
      float mn = fmaxf(mrow[r], tm);
      float rs = __expf(mrow[r] - mn);
      mrow[r] = mn;
      float ps = 0.f;
#pragma unroll
      for (int c = 0; c < 4; ++c) { float p = __expf(sf[c][r] - mn); sf[c][r] = p; ps += p; }
#pragma unroll
      for (int off = 8; off; off >>= 1) ps += __shfl_xor(ps, off, 64);
      lrow[r] = lrow[r] * rs + ps;
#pragma unroll
      for (int n = 0; n < 8; ++n) o[n][r] *= rs;
    }

    // ---- P -> wave-private LDS (bf16); same-wave DS ops in-order, no block barrier ----
#pragma unroll
    for (int c = 0; c < 4; ++c)
#pragma unroll
      for (int r = 0; r < 4; ++r)
        lP[w][4 * g + r][16 * c + col] = bf16_bits(sf[c][r]);
    __builtin_amdgcn_s_setprio(1);
#pragma unroll
    for (int kk = 0; kk < 64; kk += 32) {
      short8 pa = *reinterpret_cast<const short8*>(&lP[w][col][kk + 8 * g]);
#pragma unroll
      for (int n = 0; n < 8; ++n) {
        int dv = 16 * n + col;
        int phys = ((((kk + 8 * g) >> 3) ^ ((dv >> 3) & 7)) << 3);
        short8 bv = *reinterpret_cast<const short8*>(&lV[dv][phys]);
        o[n] = __builtin_amdgcn_mfma_f32_16x16x32_bf16(pa, bv, o[n], 0, 0, 0);
      }
    }
    __builtin_amdgcn_s_setprio(0);
  }

  // epilogue: normalize, write (B,S,H*128) bf16
#pragma unroll
  for (int r = 0; r < 4; ++r) {
    float inv = 1.0f / lrow[r];
    int srow = bb + q0 + 16 * w + 4 * g + r;
    size_t base = (size_t)srow * 2048 + h * 128;
#pragma unroll
    for (int n = 0; n < 8; ++n)
      out[base + 16 * n + col] = bf16_bits(o[n][r] * inv);
  }
}

// ---------------- host ----------------

extern "C" void kernel_launch(void* const* d_in, const int* in_sizes, int n_in,
                              void* d_out, int out_size, void* d_ws, size_t ws_size,
                              hipStream_t stream) {
  const float* x       = (const float*)d_in[0];
  const float* wq_a_w  = (const float*)d_in[1];
  const float* wq_a_b  = (const float*)d_in[2];
  const float* wq_b_w  = (const float*)d_in[3];
  const float* wq_b_b  = (const float*)d_in[4];
  const float* wkv_a_w = (const float*)d_in[5];
  const float* wkv_a_b = (const float*)d_in[6];
  const float* wkv_b_w = (const float*)d_in[7];
  const float* wkv_b_b = (const float*)d_in[8];
  const float* wo_w    = (const float*)d_in[9];
  const float* wo_b    = (const float*)d_in[10];
  float* out = (float*)d_out;

  const int BS = 4096;  // B*S = 2*2048
  char* p = (char*)d_ws;
  auto alloc = [&](size_t bytes) { char* r = p; p += (bytes + 255) & ~(size_t)255; return r; };
  unsigned short* xb    = (unsigned short*)alloc((size_t)BS * 2048 * 2);
  unsigned short* wqat  = (unsigned short*)alloc((size_t)512 * 2048 * 2);
  unsigned short* wqbt  = (unsigned short*)alloc((size_t)3072 * 512 * 2);
  unsigned short* wkvat = (unsigned short*)alloc((size_t)640 * 2048 * 2);  // padded 576->640
  unsigned short* wkvbt = (unsigned short*)alloc((size_t)4096 * 512 * 2);
  unsigned short* wot   = (unsigned short*)alloc((size_t)2048 * 2048 * 2);
  unsigned short* qa    = (unsigned short*)alloc((size_t)BS * 512 * 2);
  unsigned short* qbuf  = (unsigned short*)alloc((size_t)BS * 3072 * 2);
  unsigned short* ckv   = (unsigned short*)alloc((size_t)BS * 576 * 2);
  unsigned short* kvbuf = (unsigned short*)alloc((size_t)BS * 4096 * 2);
  unsigned short* attno = (unsigned short*)alloc((size_t)BS * 2048 * 2);
  float2* cs            = (float2*)alloc((size_t)2048 * 32 * sizeof(float2));

  k_f32_to_bf16<<<BS * 2048 / 4 / 256, 256, 0, stream>>>(x, xb, BS * 2048 / 4);
  k_transpose_bf16<<<dim3(2048 / 32, 512 / 32), 256, 0, stream>>>(wq_a_w, wqat, 2048, 512);
  k_transpose_bf16<<<dim3(512 / 32, 3072 / 32), 256, 0, stream>>>(wq_b_w, wqbt, 512, 3072);
  k_transpose_bf16<<<dim3(2048 / 32, 576 / 32), 256, 0, stream>>>(wkv_a_w, wkvat, 2048, 576);
  k_transpose_bf16<<<dim3(512 / 32, 4096 / 32), 256, 0, stream>>>(wkv_b_w, wkvbt, 512, 4096);
  k_transpose_bf16<<<dim3(2048 / 32, 2048 / 32), 256, 0, stream>>>(wo_w, wot, 2048, 2048);
  k_rope_table<<<2048 * 32 / 256, 256, 0, stream>>>(cs);

  // GEMM1: q_a = x @ wq_a + b
  k_gemm<unsigned short><<<dim3(BS / 128, 512 / 128), 256, 0, stream>>>(
      xb, 2048, wqat, wq_a_b, qa, BS, 512, 2048);
  // GEMM2: q = q_a @ wq_b + b
  k_gemm<unsigned short><<<dim3(BS / 128, 3072 / 128), 256, 0, stream>>>(
      qa, 512, wqbt, wq_b_b, qbuf, BS, 3072, 512);
  // GEMM3: ckv = x @ wkv_a + b
  k_gemm<unsigned short><<<dim3(BS / 128, (576 + 127) / 128), 256, 0, stream>>>(
      xb, 2048, wkvat, wkv_a_b, ckv, BS, 576, 2048);
  // RoPE in place
  k_rope_q<<<BS * 16 * 32 / 256, 256, 0, stream>>>(qbuf, cs);
  k_rope_k<<<BS * 32 / 256, 256, 0, stream>>>(ckv, cs);
  // GEMM4: kv = compressed_kv @ wkv_b + b
  k_gemm<unsigned short><<<dim3(BS / 128, 4096 / 128), 256, 0, stream>>>(
      ckv, 576, wkvbt, wkv_b_b, kvbuf, BS, 4096, 512);
  // attention: 512 blocks x 512 threads
  k_attn<<<2 * 16 * 16, 512, 0, stream>>>(qbuf, ckv, kvbuf, attno);
  // GEMM5: final projection, fp32 out
  k_gemm<float><<<dim3(BS / 128, 2048 / 128), 256, 0, stream>>>(
      attno, 2048, wot, wo_b, out, BS, 2048, 2048);
}

// Round 6
// 477.259 us; speedup vs baseline: 1.1618x; 1.0515x over previous
//
#include <hip/hip_runtime.h>
#include <hip/hip_bf16.h>

// MLA forward, MI355X. B=2, S=2048, DIM=2048, H=16, QK_HD=192 (128 nope + 64 rope), V_HD=128.
// R5: k_attn is LDS-throughput-bound -> 32 q-rows/wave (2 m-frags), q-tile 256,
// grid=256 (1 block/CU, single pass). Shared K/V fragment reads amortized over 2x rows.

typedef __attribute__((ext_vector_type(8))) short short8;
typedef __attribute__((ext_vector_type(4))) short short4v;
typedef __attribute__((ext_vector_type(4))) float f32x4;

#define GLOAD_LDS16(gp, lp)                                                      \
  __builtin_amdgcn_global_load_lds((const __attribute__((address_space(1))) void*)(gp), \
                                   (__attribute__((address_space(3))) void*)(lp), 16, 0, 0)

static __device__ __forceinline__ unsigned short bf16_bits(float f) {
  __hip_bfloat16 h = __float2bfloat16(f);
  return __builtin_bit_cast(unsigned short, h);
}
static __device__ __forceinline__ float bf16_to_f(unsigned short u) {
  unsigned int v = (unsigned int)u << 16;
  return __builtin_bit_cast(float, v);
}

// ---------------- conversion kernels ----------------

__global__ void k_f32_to_bf16(const float* __restrict__ in, unsigned short* __restrict__ out, int n4) {
  int i = blockIdx.x * 256 + threadIdx.x;
  if (i >= n4) return;
  float4 v = reinterpret_cast<const float4*>(in)[i];
  ushort4 o;
  o.x = bf16_bits(v.x); o.y = bf16_bits(v.y); o.z = bf16_bits(v.z); o.w = bf16_bits(v.w);
  reinterpret_cast<ushort4*>(out)[i] = o;
}

// W[K][N] fp32 -> Wt[N][K] bf16 (LDS-tiled transpose)
__global__ void k_transpose_bf16(const float* __restrict__ W, unsigned short* __restrict__ Wt,
                                 int K, int N) {
  __shared__ float tile[32][33];
  int k0 = blockIdx.x * 32, n0 = blockIdx.y * 32;
  int tx = threadIdx.x & 31, ty = threadIdx.x >> 5;  // ty 0..7
#pragma unroll
  for (int i = 0; i < 32; i += 8) {
    int k = k0 + ty + i, n = n0 + tx;
    tile[ty + i][tx] = (k < K && n < N) ? W[(size_t)k * N + n] : 0.f;
  }
  __syncthreads();
#pragma unroll
  for (int i = 0; i < 32; i += 8) {
    int n = n0 + ty + i, k = k0 + tx;
    if (n < N && k < K) Wt[(size_t)n * K + k] = bf16_bits(tile[tx][ty + i]);
  }
}

// ---------------- RoPE ----------------

__global__ void k_rope_table(float2* __restrict__ cs) {
  int idx = blockIdx.x * 256 + threadIdx.x;  // 2048*32 total
  int s = idx >> 5, i = idx & 31;
  float inv = powf(1.0e6f, -(float)(2 * i) / 64.0f);
  float a = (float)s * inv;
  cs[idx] = make_float2(cosf(a), sinf(a));
}

__global__ void k_rope_q(unsigned short* __restrict__ q, const float2* __restrict__ cs) {
  int idx = blockIdx.x * 256 + threadIdx.x;  // BS*16*32
  int i = idx & 31;
  int h = (idx >> 5) & 15;
  int bs = idx >> 9;
  int s = bs & 2047;
  size_t base = (size_t)bs * 3072 + h * 192 + 128 + 2 * i;
  float xr = bf16_to_f(q[base]);
  float xi = bf16_to_f(q[base + 1]);
  float2 c = cs[(s << 5) + i];
  q[base]     = bf16_bits(xr * c.x - xi * c.y);
  q[base + 1] = bf16_bits(xr * c.y + xi * c.x);
}

__global__ void k_rope_k(unsigned short* __restrict__ ckv, const float2* __restrict__ cs) {
  int idx = blockIdx.x * 256 + threadIdx.x;  // BS*32
  int i = idx & 31;
  int bs = idx >> 5;
  int s = bs & 2047;
  size_t base = (size_t)bs * 576 + 512 + 2 * i;
  float xr = bf16_to_f(ckv[base]);
  float xi = bf16_to_f(ckv[base + 1]);
  float2 c = cs[(s << 5) + i];
  ckv[base]     = bf16_bits(xr * c.x - xi * c.y);
  ckv[base + 1] = bf16_bits(xr * c.y + xi * c.x);
}

// ---------------- GEMM: C[M][N] = A[M][K](lda) @ Wt[N][K]^T + bias ----------------
// (unchanged R2 structure: global_load_lds w16, linear LDS + pre-swizzled source)

template <typename OutT>
__global__ __launch_bounds__(256, 2) void k_gemm(const unsigned short* __restrict__ A, int lda,
                                                 const unsigned short* __restrict__ Wt,
                                                 const float* __restrict__ bias,
                                                 OutT* __restrict__ C, int M, int N, int K) {
  __shared__ unsigned short lA[128][64];
  __shared__ unsigned short lB[128][64];
  int m0 = blockIdx.x * 128, n0 = blockIdx.y * 128;
  int t = threadIdx.x;
  int lane = t & 63, wid = t >> 6;
  int g = lane >> 4, col = lane & 15;
  int wr = wid >> 1, wc = wid & 1;
  int srow = lane >> 3;                 // 0..7 within wave chunk
  int schunk = (lane & 7) ^ srow;       // inverse-swizzled source chunk
  f32x4 acc[4][4] = {};

  for (int kt = 0; kt < K; kt += 64) {
#pragma unroll
    for (int i = 0; i < 4; ++i) {
      int rowb = 32 * wid + 8 * i;      // wave-uniform LDS row base
      int row = rowb + srow;
      GLOAD_LDS16(&A[(size_t)(m0 + row) * lda + kt + 8 * schunk], &lA[rowb][0]);
      GLOAD_LDS16(&Wt[(size_t)(n0 + row) * K + kt + 8 * schunk], &lB[rowb][0]);
    }
    __syncthreads();
#pragma unroll
    for (int kk = 0; kk < 64; kk += 32) {
      int ch = (kk >> 3) + g;
      int sl = 8 * (ch ^ (col & 7));
      short8 a[4], b[4];
#pragma unroll
      for (int mf = 0; mf < 4; ++mf)
        a[mf] = *reinterpret_cast<const short8*>(&lA[64 * wr + 16 * mf + col][sl]);
#pragma unroll
      for (int nf = 0; nf < 4; ++nf)
        b[nf] = *reinterpret_cast<const short8*>(&lB[64 * wc + 16 * nf + col][sl]);
#pragma unroll
      for (int mf = 0; mf < 4; ++mf)
#pragma unroll
        for (int nf = 0; nf < 4; ++nf)
          acc[mf][nf] = __builtin_amdgcn_mfma_f32_16x16x32_bf16(a[mf], b[nf], acc[mf][nf], 0, 0, 0);
    }
    __syncthreads();
  }

#pragma unroll
  for (int mf = 0; mf < 4; ++mf) {
#pragma unroll
    for (int nf = 0; nf < 4; ++nf) {
      int n = n0 + 64 * wc + 16 * nf + col;
      if (n >= N) continue;
      float bv = bias[n];
#pragma unroll
      for (int r = 0; r < 4; ++r) {
        int m = m0 + 64 * wr + 16 * mf + 4 * g + r;
        float v = acc[mf][nf][r] + bv;
        if constexpr (sizeof(OutT) == 4)
          C[(size_t)m * N + n] = v;
        else
          C[(size_t)m * N + n] = bf16_bits(v);
      }
    }
  }
}

// ---------------- flash attention (R5) ----------------
// grid = B*H*(S/256) = 256 blocks (1/CU), 512 threads = 8 waves.
// Wave w owns 32 q-rows [q0+32w, +32) as 2 m-fragments; shared K/V fragment
// reads amortized over both (B-operand read once, 2 MFMAs). 2-phase reg prefetch.

__global__ __launch_bounds__(512, 2) void k_attn(const unsigned short* __restrict__ q,
                                                 const unsigned short* __restrict__ ckv,
                                                 const unsigned short* __restrict__ kv,
                                                 unsigned short* __restrict__ out) {
  __shared__ unsigned short lK[64][200];    // 64 kv-rows x 192 dims (+8 pad)
  __shared__ unsigned short lV[128][72];    // V^T swizzled: 128 dv x 64 kv (+8 pad)
  __shared__ unsigned short lP[8][32][72];  // per-wave P 32x64 (+8 pad), wave-private
  int bx = blockIdx.x;
  int qt = bx & 7, h = (bx >> 3) & 15, b = bx >> 7;
  int t = threadIdx.x, lane = t & 63, w = t >> 6;
  int g = lane >> 4, col = lane & 15;
  int q0 = qt * 256;
  int bb = b * 2048;
  const float scale = 0.08838834764831845f;  // 1/sqrt(128)

  short8 qf[2][6];
#pragma unroll
  for (int m = 0; m < 2; ++m) {
    int srow = bb + q0 + 32 * w + 16 * m + col;
    size_t base = ((size_t)srow * 16 + h) * 192 + 8 * g;
#pragma unroll
    for (int j = 0; j < 6; ++j)
      qf[m][j] = *reinterpret_cast<const short8*>(&q[base + 32 * j]);
  }

  // staging registers
  short8 kreg[3];
  short4v vreg0[2], vreg1[2];

  auto load_tile = [&](int k0) {
#pragma unroll
    for (int it = 0; it < 3; ++it) {
      int c = t + 512 * it;
      int row = c / 24, cc = c % 24;
      int s = bb + k0 + row;
      const unsigned short* src;
      if (cc < 16) src = &kv[((size_t)s * 16 + h) * 256 + cc * 8];
      else         src = &ckv[(size_t)s * 576 + 512 + (cc - 16) * 8];
      kreg[it] = *reinterpret_cast<const short8*>(src);
    }
#pragma unroll
    for (int it = 0; it < 2; ++it) {
      int c = t + 512 * it;
      int kp = c >> 5, dv0 = (c & 31) * 4;
      size_t vb = ((size_t)(bb + k0 + 2 * kp) * 16 + h) * 256 + 128 + dv0;
      vreg0[it] = *reinterpret_cast<const short4v*>(&kv[vb]);
      vreg1[it] = *reinterpret_cast<const short4v*>(&kv[vb + 4096]);  // next kv row
    }
  };

  load_tile(0);

  f32x4 o[2][8] = {};
  float mrow[2][4] = {{-1e30f, -1e30f, -1e30f, -1e30f}, {-1e30f, -1e30f, -1e30f, -1e30f}};
  float lrow[2][4] = {};

  for (int k0 = 0; k0 < 2048; k0 += 64) {
    __syncthreads();  // prior tile's LDS reads complete
    // ---- write staged regs -> LDS ----
#pragma unroll
    for (int it = 0; it < 3; ++it) {
      int c = t + 512 * it;
      int row = c / 24, cc = c % 24;
      *reinterpret_cast<short8*>(&lK[row][cc * 8]) = kreg[it];
    }
#pragma unroll
    for (int it = 0; it < 2; ++it) {
      int c = t + 512 * it;
      int kp = c >> 5, dv0 = (c & 31) * 4;
      int k2 = 2 * kp;
#pragma unroll
      for (int j = 0; j < 4; ++j) {
        int dv = dv0 + j;
        int phys = (((k2 >> 3) ^ ((dv >> 3) & 7)) << 3) + (k2 & 7);
        unsigned int pw = (unsigned int)(unsigned short)vreg0[it][j] |
                          ((unsigned int)(unsigned short)vreg1[it][j] << 16);
        *reinterpret_cast<unsigned int*>(&lV[dv][phys]) = pw;
      }
    }
    __syncthreads();
    // ---- issue next tile's global loads (hidden under compute) ----
    if (k0 + 64 < 2048) load_tile(k0 + 64);
    __builtin_amdgcn_sched_barrier(0);  // keep loads issued before compute

    // ---- S = Q K^T: 32 q-rows x 64 k per wave; B-frag shared across m ----
    f32x4 sf[2][4] = {};
    __builtin_amdgcn_s_setprio(1);
#pragma unroll
    for (int c = 0; c < 4; ++c) {
#pragma unroll
      for (int j = 0; j < 6; ++j) {
        short8 bfr = *reinterpret_cast<const short8*>(&lK[16 * c + col][32 * j + 8 * g]);
#pragma unroll
        for (int m = 0; m < 2; ++m)
          sf[m][c] = __builtin_amdgcn_mfma_f32_16x16x32_bf16(qf[m][j], bfr, sf[m][c], 0, 0, 0);
      }
    }
    __builtin_amdgcn_s_setprio(0);

    // ---- online softmax; row of lane = q0+32w+16m+4g+r ----
#pragma unroll
    for (int m = 0; m < 2; ++m) {
#pragma unroll
      for (int r = 0; r < 4; ++r) {
        float tm = -1e30f;
#pragma unroll
        for (int c = 0; c < 4; ++c) { sf[m][c][r] *= scale; tm = fmaxf(tm, sf[m][c][r]); }
#pragma unroll
        for (int off = 8; off; off >>= 1) tm = fmaxf(tm, __shfl_xor(tm, off, 64));
        float mn = fmaxf(mrow[m][r], tm);
        float rs = __expf(mrow[m][r] - mn);
        mrow[m][r] = mn;
        float ps = 0.f;
#pragma unroll
        for (int c = 0; c < 4; ++c) { float p = __expf(sf[m][c][r] - mn); sf[m][c][r] = p; ps += p; }
#pragma unroll
        for (int off = 8; off; off >>= 1) ps += __shfl_xor(ps, off, 64);
        lrow[m][r] = lrow[m][r] * rs + ps;
#pragma unroll
        for (int n = 0; n < 8; ++n) o[m][n][r] *= rs;
      }
    }

    // ---- P -> wave-private LDS (bf16); same-wave DS ops in-order ----
#pragma unroll
    for (int m = 0; m < 2; ++m)
#pragma unroll
      for (int c = 0; c < 4; ++c)
#pragma unroll
        for (int r = 0; r < 4; ++r)
          lP[w][16 * m + 4 * g + r][16 * c + col] = bf16_bits(sf[m][c][r]);
    __builtin_amdgcn_s_setprio(1);
#pragma unroll
    for (int kk = 0; kk < 64; kk += 32) {
      short8 pa[2];
#pragma unroll
      for (int m = 0; m < 2; ++m)
        pa[m] = *reinterpret_cast<const short8*>(&lP[w][16 * m + col][kk + 8 * g]);
#pragma unroll
      for (int n = 0; n < 8; ++n) {
        int dv = 16 * n + col;
        int phys = ((((kk + 8 * g) >> 3) ^ ((dv >> 3) & 7)) << 3);
        short8 bv = *reinterpret_cast<const short8*>(&lV[dv][phys]);
#pragma unroll
        for (int m = 0; m < 2; ++m)
          o[m][n] = __builtin_amdgcn_mfma_f32_16x16x32_bf16(pa[m], bv, o[m][n], 0, 0, 0);
      }
    }
    __builtin_amdgcn_s_setprio(0);
  }

  // epilogue: normalize, write (B,S,H*128) bf16
#pragma unroll
  for (int m = 0; m < 2; ++m) {
#pragma unroll
    for (int r = 0; r < 4; ++r) {
      float inv = 1.0f / lrow[m][r];
      int srow = bb + q0 + 32 * w + 16 * m + 4 * g + r;
      size_t base = (size_t)srow * 2048 + h * 128;
#pragma unroll
      for (int n = 0; n < 8; ++n)
        out[base + 16 * n + col] = bf16_bits(o[m][n][r] * inv);
    }
  }
}

// ---------------- host ----------------

extern "C" void kernel_launch(void* const* d_in, const int* in_sizes, int n_in,
                              void* d_out, int out_size, void* d_ws, size_t ws_size,
                              hipStream_t stream) {
  const float* x       = (const float*)d_in[0];
  const float* wq_a_w  = (const float*)d_in[1];
  const float* wq_a_b  = (const float*)d_in[2];
  const float* wq_b_w  = (const float*)d_in[3];
  const float* wq_b_b  = (const float*)d_in[4];
  const float* wkv_a_w = (const float*)d_in[5];
  const float* wkv_a_b = (const float*)d_in[6];
  const float* wkv_b_w = (const float*)d_in[7];
  const float* wkv_b_b = (const float*)d_in[8];
  const float* wo_w    = (const float*)d_in[9];
  const float* wo_b    = (const float*)d_in[10];
  float* out = (float*)d_out;

  const int BS = 4096;  // B*S = 2*2048
  char* p = (char*)d_ws;
  auto alloc = [&](size_t bytes) { char* r = p; p += (bytes + 255) & ~(size_t)255; return r; };
  unsigned short* xb    = (unsigned short*)alloc((size_t)BS * 2048 * 2);
  unsigned short* wqat  = (unsigned short*)alloc((size_t)512 * 2048 * 2);
  unsigned short* wqbt  = (unsigned short*)alloc((size_t)3072 * 512 * 2);
  unsigned short* wkvat = (unsigned short*)alloc((size_t)640 * 2048 * 2);  // padded 576->640
  unsigned short* wkvbt = (unsigned short*)alloc((size_t)4096 * 512 * 2);
  unsigned short* wot   = (unsigned short*)alloc((size_t)2048 * 2048 * 2);
  unsigned short* qa    = (unsigned short*)alloc((size_t)BS * 512 * 2);
  unsigned short* qbuf  = (unsigned short*)alloc((size_t)BS * 3072 * 2);
  unsigned short* ckv   = (unsigned short*)alloc((size_t)BS * 576 * 2);
  unsigned short* kvbuf = (unsigned short*)alloc((size_t)BS * 4096 * 2);
  unsigned short* attno = (unsigned short*)alloc((size_t)BS * 2048 * 2);
  float2* cs            = (float2*)alloc((size_t)2048 * 32 * sizeof(float2));

  k_f32_to_bf16<<<BS * 2048 / 4 / 256, 256, 0, stream>>>(x, xb, BS * 2048 / 4);
  k_transpose_bf16<<<dim3(2048 / 32, 512 / 32), 256, 0, stream>>>(wq_a_w, wqat, 2048, 512);
  k_transpose_bf16<<<dim3(512 / 32, 3072 / 32), 256, 0, stream>>>(wq_b_w, wqbt, 512, 3072);
  k_transpose_bf16<<<dim3(2048 / 32, 576 / 32), 256, 0, stream>>>(wkv_a_w, wkvat, 2048, 576);
  k_transpose_bf16<<<dim3(512 / 32, 4096 / 32), 256, 0, stream>>>(wkv_b_w, wkvbt, 512, 4096);
  k_transpose_bf16<<<dim3(2048 / 32, 2048 / 32), 256, 0, stream>>>(wo_w, wot, 2048, 2048);
  k_rope_table<<<2048 * 32 / 256, 256, 0, stream>>>(cs);

  // GEMM1: q_a = x @ wq_a + b
  k_gemm<unsigned short><<<dim3(BS / 128, 512 / 128), 256, 0, stream>>>(
      xb, 2048, wqat, wq_a_b, qa, BS, 512, 2048);
  // GEMM2: q = q_a @ wq_b + b
  k_gemm<unsigned short><<<dim3(BS / 128, 3072 / 128), 256, 0, stream>>>(
      qa, 512, wqbt, wq_b_b, qbuf, BS, 3072, 512);
  // GEMM3: ckv = x @ wkv_a + b
  k_gemm<unsigned short><<<dim3(BS / 128, (576 + 127) / 128), 256, 0, stream>>>(
      xb, 2048, wkvat, wkv_a_b, ckv, BS, 576, 2048);
  // RoPE in place
  k_rope_q<<<BS * 16 * 32 / 256, 256, 0, stream>>>(qbuf, cs);
  k_rope_k<<<BS * 32 / 256, 256, 0, stream>>>(ckv, cs);
  // GEMM4: kv = compressed_kv @ wkv_b + b
  k_gemm<unsigned short><<<dim3(BS / 128, 4096 / 128), 256, 0, stream>>>(
      ckv, 576, wkvbt, wkv_b_b, kvbuf, BS, 4096, 512);
  // attention: 256 blocks x 512 threads (1 block/CU, single pass)
  k_attn<<<2 * 16 * 8, 512, 0, stream>>>(qbuf, ckv, kvbuf, attno);
  // GEMM5: final projection, fp32 out
  k_gemm<float><<<dim3(BS / 128, 2048 / 128), 256, 0, stream>>>(
      attno, 2048, wot, wo_b, out, BS, 2048, 2048);
}

// Round 7
// 407.311 us; speedup vs baseline: 1.3614x; 1.1717x over previous
//
#include <hip/hip_runtime.h>
#include <hip/hip_bf16.h>

// MLA forward, MI355X. B=2, S=2048, DIM=2048, H=16, QK_HD=192 (128 nope + 64 rope), V_HD=128.
// R6: (a) GEMM1+GEMM3 fused into one N=1088 dispatch (both read xb; were 128/160-block
//     half-idle sequential dispatches); (b) attn lP XOR-swizzled (kills 4-way write /
//     folded read conflicts); (c) softmax sum-shfl deferred to epilogue (rs is row-uniform,
//     per-lane partials commute with rescale).

typedef __attribute__((ext_vector_type(8))) short short8;
typedef __attribute__((ext_vector_type(4))) short short4v;
typedef __attribute__((ext_vector_type(4))) float f32x4;

#define GLOAD_LDS16(gp, lp)                                                      \
  __builtin_amdgcn_global_load_lds((const __attribute__((address_space(1))) void*)(gp), \
                                   (__attribute__((address_space(3))) void*)(lp), 16, 0, 0)

static __device__ __forceinline__ unsigned short bf16_bits(float f) {
  __hip_bfloat16 h = __float2bfloat16(f);
  return __builtin_bit_cast(unsigned short, h);
}
static __device__ __forceinline__ float bf16_to_f(unsigned short u) {
  unsigned int v = (unsigned int)u << 16;
  return __builtin_bit_cast(float, v);
}

// ---------------- conversion kernels ----------------

__global__ void k_f32_to_bf16(const float* __restrict__ in, unsigned short* __restrict__ out, int n4) {
  int i = blockIdx.x * 256 + threadIdx.x;
  if (i >= n4) return;
  float4 v = reinterpret_cast<const float4*>(in)[i];
  ushort4 o;
  o.x = bf16_bits(v.x); o.y = bf16_bits(v.y); o.z = bf16_bits(v.z); o.w = bf16_bits(v.w);
  reinterpret_cast<ushort4*>(out)[i] = o;
}

// W[K][N] fp32 -> Wt[N][K] bf16 (LDS-tiled transpose)
__global__ void k_transpose_bf16(const float* __restrict__ W, unsigned short* __restrict__ Wt,
                                 int K, int N) {
  __shared__ float tile[32][33];
  int k0 = blockIdx.x * 32, n0 = blockIdx.y * 32;
  int tx = threadIdx.x & 31, ty = threadIdx.x >> 5;  // ty 0..7
#pragma unroll
  for (int i = 0; i < 32; i += 8) {
    int k = k0 + ty + i, n = n0 + tx;
    tile[ty + i][tx] = (k < K && n < N) ? W[(size_t)k * N + n] : 0.f;
  }
  __syncthreads();
#pragma unroll
  for (int i = 0; i < 32; i += 8) {
    int n = n0 + ty + i, k = k0 + tx;
    if (n < N && k < K) Wt[(size_t)n * K + k] = bf16_bits(tile[tx][ty + i]);
  }
}

// ---------------- RoPE ----------------

__global__ void k_rope_table(float2* __restrict__ cs) {
  int idx = blockIdx.x * 256 + threadIdx.x;  // 2048*32 total
  int s = idx >> 5, i = idx & 31;
  float inv = powf(1.0e6f, -(float)(2 * i) / 64.0f);
  float a = (float)s * inv;
  cs[idx] = make_float2(cosf(a), sinf(a));
}

__global__ void k_rope_q(unsigned short* __restrict__ q, const float2* __restrict__ cs) {
  int idx = blockIdx.x * 256 + threadIdx.x;  // BS*16*32
  int i = idx & 31;
  int h = (idx >> 5) & 15;
  int bs = idx >> 9;
  int s = bs & 2047;
  size_t base = (size_t)bs * 3072 + h * 192 + 128 + 2 * i;
  float xr = bf16_to_f(q[base]);
  float xi = bf16_to_f(q[base + 1]);
  float2 c = cs[(s << 5) + i];
  q[base]     = bf16_bits(xr * c.x - xi * c.y);
  q[base + 1] = bf16_bits(xr * c.y + xi * c.x);
}

__global__ void k_rope_k(unsigned short* __restrict__ ckv, const float2* __restrict__ cs) {
  int idx = blockIdx.x * 256 + threadIdx.x;  // BS*32
  int i = idx & 31;
  int bs = idx >> 5;
  int s = bs & 2047;
  size_t base = (size_t)bs * 576 + 512 + 2 * i;
  float xr = bf16_to_f(ckv[base]);
  float xi = bf16_to_f(ckv[base + 1]);
  float2 c = cs[(s << 5) + i];
  ckv[base]     = bf16_bits(xr * c.x - xi * c.y);
  ckv[base + 1] = bf16_bits(xr * c.y + xi * c.x);
}

// ---------------- GEMM: C[M][N] = A[M][K](lda) @ Wt[N][K]^T + bias ----------------
// (R2 structure: global_load_lds w16, linear LDS + pre-swizzled source)

template <typename OutT>
__global__ __launch_bounds__(256, 2) void k_gemm(const unsigned short* __restrict__ A, int lda,
                                                 const unsigned short* __restrict__ Wt,
                                                 const float* __restrict__ bias,
                                                 OutT* __restrict__ C, int M, int N, int K) {
  __shared__ unsigned short lA[128][64];
  __shared__ unsigned short lB[128][64];
  int m0 = blockIdx.x * 128, n0 = blockIdx.y * 128;
  int t = threadIdx.x;
  int lane = t & 63, wid = t >> 6;
  int g = lane >> 4, col = lane & 15;
  int wr = wid >> 1, wc = wid & 1;
  int srow = lane >> 3;
  int schunk = (lane & 7) ^ srow;
  f32x4 acc[4][4] = {};

  for (int kt = 0; kt < K; kt += 64) {
#pragma unroll
    for (int i = 0; i < 4; ++i) {
      int rowb = 32 * wid + 8 * i;
      int row = rowb + srow;
      GLOAD_LDS16(&A[(size_t)(m0 + row) * lda + kt + 8 * schunk], &lA[rowb][0]);
      GLOAD_LDS16(&Wt[(size_t)(n0 + row) * K + kt + 8 * schunk], &lB[rowb][0]);
    }
    __syncthreads();
#pragma unroll
    for (int kk = 0; kk < 64; kk += 32) {
      int ch = (kk >> 3) + g;
      int sl = 8 * (ch ^ (col & 7));
      short8 a[4], b[4];
#pragma unroll
      for (int mf = 0; mf < 4; ++mf)
        a[mf] = *reinterpret_cast<const short8*>(&lA[64 * wr + 16 * mf + col][sl]);
#pragma unroll
      for (int nf = 0; nf < 4; ++nf)
        b[nf] = *reinterpret_cast<const short8*>(&lB[64 * wc + 16 * nf + col][sl]);
#pragma unroll
      for (int mf = 0; mf < 4; ++mf)
#pragma unroll
        for (int nf = 0; nf < 4; ++nf)
          acc[mf][nf] = __builtin_amdgcn_mfma_f32_16x16x32_bf16(a[mf], b[nf], acc[mf][nf], 0, 0, 0);
    }
    __syncthreads();
  }

#pragma unroll
  for (int mf = 0; mf < 4; ++mf) {
#pragma unroll
    for (int nf = 0; nf < 4; ++nf) {
      int n = n0 + 64 * wc + 16 * nf + col;
      if (n >= N) continue;
      float bv = bias[n];
#pragma unroll
      for (int r = 0; r < 4; ++r) {
        int m = m0 + 64 * wr + 16 * mf + 4 * g + r;
        float v = acc[mf][nf][r] + bv;
        if constexpr (sizeof(OutT) == 4)
          C[(size_t)m * N + n] = v;
        else
          C[(size_t)m * N + n] = bf16_bits(v);
      }
    }
  }
}

// Fused GEMM1+GEMM3: A=xb (K=2048), Wf[1152][2048] = [wqa^T; wkva^T], split outputs.
__global__ __launch_bounds__(256, 2) void k_gemm_qkv(const unsigned short* __restrict__ A,
                                                     const unsigned short* __restrict__ Wf,
                                                     const float* __restrict__ biasf,
                                                     unsigned short* __restrict__ qa,
                                                     unsigned short* __restrict__ ckv) {
  __shared__ unsigned short lA[128][64];
  __shared__ unsigned short lB[128][64];
  int m0 = blockIdx.x * 128, n0 = blockIdx.y * 128;
  int t = threadIdx.x;
  int lane = t & 63, wid = t >> 6;
  int g = lane >> 4, col = lane & 15;
  int wr = wid >> 1, wc = wid & 1;
  int srow = lane >> 3;
  int schunk = (lane & 7) ^ srow;
  f32x4 acc[4][4] = {};

  for (int kt = 0; kt < 2048; kt += 64) {
#pragma unroll
    for (int i = 0; i < 4; ++i) {
      int rowb = 32 * wid + 8 * i;
      int row = rowb + srow;
      GLOAD_LDS16(&A[(size_t)(m0 + row) * 2048 + kt + 8 * schunk], &lA[rowb][0]);
      GLOAD_LDS16(&Wf[(size_t)(n0 + row) * 2048 + kt + 8 * schunk], &lB[rowb][0]);
    }
    __syncthreads();
#pragma unroll
    for (int kk = 0; kk < 64; kk += 32) {
      int ch = (kk >> 3) + g;
      int sl = 8 * (ch ^ (col & 7));
      short8 a[4], b[4];
#pragma unroll
      for (int mf = 0; mf < 4; ++mf)
        a[mf] = *reinterpret_cast<const short8*>(&lA[64 * wr + 16 * mf + col][sl]);
#pragma unroll
      for (int nf = 0; nf < 4; ++nf)
        b[nf] = *reinterpret_cast<const short8*>(&lB[64 * wc + 16 * nf + col][sl]);
#pragma unroll
      for (int mf = 0; mf < 4; ++mf)
#pragma unroll
        for (int nf = 0; nf < 4; ++nf)
          acc[mf][nf] = __builtin_amdgcn_mfma_f32_16x16x32_bf16(a[mf], b[nf], acc[mf][nf], 0, 0, 0);
    }
    __syncthreads();
  }

#pragma unroll
  for (int mf = 0; mf < 4; ++mf) {
#pragma unroll
    for (int nf = 0; nf < 4; ++nf) {
      int n = n0 + 64 * wc + 16 * nf + col;
      if (n >= 1088) continue;
      float bv = biasf[n];
#pragma unroll
      for (int r = 0; r < 4; ++r) {
        int m = m0 + 64 * wr + 16 * mf + 4 * g + r;
        float v = acc[mf][nf][r] + bv;
        if (n < 512) qa[(size_t)m * 512 + n] = bf16_bits(v);
        else         ckv[(size_t)m * 576 + (n - 512)] = bf16_bits(v);
      }
    }
  }
}

// ---------------- flash attention (R6) ----------------
// grid = B*H*(S/256) = 256 blocks (1/CU), 512 threads = 8 waves; 32 q-rows/wave.
// lP now chunk-XOR-swizzled: chunk ck' = ck ^ (row>>2 & 7); sum-shfl deferred to epilogue.

__global__ __launch_bounds__(512, 2) void k_attn(const unsigned short* __restrict__ q,
                                                 const unsigned short* __restrict__ ckv,
                                                 const unsigned short* __restrict__ kv,
                                                 unsigned short* __restrict__ out) {
  __shared__ unsigned short lK[64][200];
  __shared__ unsigned short lV[128][72];
  __shared__ unsigned short lP[8][32][72];
  int bx = blockIdx.x;
  int qt = bx & 7, h = (bx >> 3) & 15, b = bx >> 7;
  int t = threadIdx.x, lane = t & 63, w = t >> 6;
  int g = lane >> 4, col = lane & 15;
  int q0 = qt * 256;
  int bb = b * 2048;
  const float scale = 0.08838834764831845f;  // 1/sqrt(128)

  short8 qf[2][6];
#pragma unroll
  for (int m = 0; m < 2; ++m) {
    int srow = bb + q0 + 32 * w + 16 * m + col;
    size_t base = ((size_t)srow * 16 + h) * 192 + 8 * g;
#pragma unroll
    for (int j = 0; j < 6; ++j)
      qf[m][j] = *reinterpret_cast<const short8*>(&q[base + 32 * j]);
  }

  short8 kreg[3];
  short4v vreg0[2], vreg1[2];

  auto load_tile = [&](int k0) {
#pragma unroll
    for (int it = 0; it < 3; ++it) {
      int c = t + 512 * it;
      int row = c / 24, cc = c % 24;
      int s = bb + k0 + row;
      const unsigned short* src;
      if (cc < 16) src = &kv[((size_t)s * 16 + h) * 256 + cc * 8];
      else         src = &ckv[(size_t)s * 576 + 512 + (cc - 16) * 8];
      kreg[it] = *reinterpret_cast<const short8*>(src);
    }
#pragma unroll
    for (int it = 0; it < 2; ++it) {
      int c = t + 512 * it;
      int kp = c >> 5, dv0 = (c & 31) * 4;
      size_t vb = ((size_t)(bb + k0 + 2 * kp) * 16 + h) * 256 + 128 + dv0;
      vreg0[it] = *reinterpret_cast<const short4v*>(&kv[vb]);
      vreg1[it] = *reinterpret_cast<const short4v*>(&kv[vb + 4096]);
    }
  };

  load_tile(0);

  f32x4 o[2][8] = {};
  float mrow[2][4] = {{-1e30f, -1e30f, -1e30f, -1e30f}, {-1e30f, -1e30f, -1e30f, -1e30f}};
  float lrow[2][4] = {};  // per-lane PARTIAL sums (reduced in epilogue)

  for (int k0 = 0; k0 < 2048; k0 += 64) {
    __syncthreads();
#pragma unroll
    for (int it = 0; it < 3; ++it) {
      int c = t + 512 * it;
      int row = c / 24, cc = c % 24;
      *reinterpret_cast<short8*>(&lK[row][cc * 8]) = kreg[it];
    }
#pragma unroll
    for (int it = 0; it < 2; ++it) {
      int c = t + 512 * it;
      int kp = c >> 5, dv0 = (c & 31) * 4;
      int k2 = 2 * kp;
#pragma unroll
      for (int j = 0; j < 4; ++j) {
        int dv = dv0 + j;
        int phys = (((k2 >> 3) ^ ((dv >> 3) & 7)) << 3) + (k2 & 7);
        unsigned int pw = (unsigned int)(unsigned short)vreg0[it][j] |
                          ((unsigned int)(unsigned short)vreg1[it][j] << 16);
        *reinterpret_cast<unsigned int*>(&lV[dv][phys]) = pw;
      }
    }
    __syncthreads();
    if (k0 + 64 < 2048) load_tile(k0 + 64);
    __builtin_amdgcn_sched_barrier(0);

    // ---- S = Q K^T ----
    f32x4 sf[2][4] = {};
    __builtin_amdgcn_s_setprio(1);
#pragma unroll
    for (int c = 0; c < 4; ++c) {
#pragma unroll
      for (int j = 0; j < 6; ++j) {
        short8 bfr = *reinterpret_cast<const short8*>(&lK[16 * c + col][32 * j + 8 * g]);
#pragma unroll
        for (int m = 0; m < 2; ++m)
          sf[m][c] = __builtin_amdgcn_mfma_f32_16x16x32_bf16(qf[m][j], bfr, sf[m][c], 0, 0, 0);
      }
    }
    __builtin_amdgcn_s_setprio(0);

    // ---- online softmax (max-shfl only; sum kept per-lane partial) ----
#pragma unroll
    for (int m = 0; m < 2; ++m) {
#pragma unroll
      for (int r = 0; r < 4; ++r) {
        float tm = -1e30f;
#pragma unroll
        for (int c = 0; c < 4; ++c) { sf[m][c][r] *= scale; tm = fmaxf(tm, sf[m][c][r]); }
#pragma unroll
        for (int off = 8; off; off >>= 1) tm = fmaxf(tm, __shfl_xor(tm, off, 64));
        float mn = fmaxf(mrow[m][r], tm);
        float rs = __expf(mrow[m][r] - mn);
        mrow[m][r] = mn;
        float ps = 0.f;
#pragma unroll
        for (int c = 0; c < 4; ++c) { float p = __expf(sf[m][c][r] - mn); sf[m][c][r] = p; ps += p; }
        lrow[m][r] = lrow[m][r] * rs + ps;   // per-lane partial; rs is row-uniform
#pragma unroll
        for (int n = 0; n < 8; ++n) o[m][n][r] *= rs;
      }
    }

    // ---- P -> wave-private LDS, chunk-XOR swizzled ----
#pragma unroll
    for (int m = 0; m < 2; ++m)
#pragma unroll
      for (int c = 0; c < 4; ++c)
#pragma unroll
        for (int r = 0; r < 4; ++r) {
          int rowp = 16 * m + 4 * g + r;
          int k16 = 16 * c + col;
          int phys = ((((k16 >> 3) ^ ((rowp >> 2) & 7))) << 3) + (k16 & 7);
          lP[w][rowp][phys] = bf16_bits(sf[m][c][r]);
        }
    __builtin_amdgcn_s_setprio(1);
#pragma unroll
    for (int kk = 0; kk < 64; kk += 32) {
      short8 pa[2];
#pragma unroll
      for (int m = 0; m < 2; ++m) {
        int rowp = 16 * m + col;
        int ck = ((kk + 8 * g) >> 3) ^ ((rowp >> 2) & 7);
        pa[m] = *reinterpret_cast<const short8*>(&lP[w][rowp][ck << 3]);
      }
#pragma unroll
      for (int n = 0; n < 8; ++n) {
        int dv = 16 * n + col;
        int phys = ((((kk + 8 * g) >> 3) ^ ((dv >> 3) & 7)) << 3);
        short8 bv = *reinterpret_cast<const short8*>(&lV[dv][phys]);
#pragma unroll
        for (int m = 0; m < 2; ++m)
          o[m][n] = __builtin_amdgcn_mfma_f32_16x16x32_bf16(pa[m], bv, o[m][n], 0, 0, 0);
      }
    }
    __builtin_amdgcn_s_setprio(0);
  }

  // epilogue: reduce row-sums once, normalize, write (B,S,H*128) bf16
#pragma unroll
  for (int m = 0; m < 2; ++m) {
#pragma unroll
    for (int r = 0; r < 4; ++r) {
      float tot = lrow[m][r];
#pragma unroll
      for (int off = 8; off; off >>= 1) tot += __shfl_xor(tot, off, 64);
      float inv = 1.0f / tot;
      int srow = bb + q0 + 32 * w + 16 * m + 4 * g + r;
      size_t base = (size_t)srow * 2048 + h * 128;
#pragma unroll
      for (int n = 0; n < 8; ++n)
        out[base + 16 * n + col] = bf16_bits(o[m][n][r] * inv);
    }
  }
}

// ---------------- host ----------------

extern "C" void kernel_launch(void* const* d_in, const int* in_sizes, int n_in,
                              void* d_out, int out_size, void* d_ws, size_t ws_size,
                              hipStream_t stream) {
  const float* x       = (const float*)d_in[0];
  const float* wq_a_w  = (const float*)d_in[1];
  const float* wq_a_b  = (const float*)d_in[2];
  const float* wq_b_w  = (const float*)d_in[3];
  const float* wq_b_b  = (const float*)d_in[4];
  const float* wkv_a_w = (const float*)d_in[5];
  const float* wkv_a_b = (const float*)d_in[6];
  const float* wkv_b_w = (const float*)d_in[7];
  const float* wkv_b_b = (const float*)d_in[8];
  const float* wo_w    = (const float*)d_in[9];
  const float* wo_b    = (const float*)d_in[10];
  float* out = (float*)d_out;

  const int BS = 4096;  // B*S = 2*2048
  char* p = (char*)d_ws;
  auto alloc = [&](size_t bytes) { char* r = p; p += (bytes + 255) & ~(size_t)255; return r; };
  unsigned short* xb     = (unsigned short*)alloc((size_t)BS * 2048 * 2);
  unsigned short* wfused = (unsigned short*)alloc((size_t)1152 * 2048 * 2);  // [wqa^T; wkva^T]
  unsigned short* wqbt   = (unsigned short*)alloc((size_t)3072 * 512 * 2);
  unsigned short* wkvbt  = (unsigned short*)alloc((size_t)4096 * 512 * 2);
  unsigned short* wot    = (unsigned short*)alloc((size_t)2048 * 2048 * 2);
  float* biasf           = (float*)alloc((size_t)1152 * sizeof(float));
  unsigned short* qa     = (unsigned short*)alloc((size_t)BS * 512 * 2);
  unsigned short* qbuf   = (unsigned short*)alloc((size_t)BS * 3072 * 2);
  unsigned short* ckv    = (unsigned short*)alloc((size_t)BS * 576 * 2);
  unsigned short* kvbuf  = (unsigned short*)alloc((size_t)BS * 4096 * 2);
  unsigned short* attno  = (unsigned short*)alloc((size_t)BS * 2048 * 2);
  float2* cs             = (float2*)alloc((size_t)2048 * 32 * sizeof(float2));

  k_f32_to_bf16<<<BS * 2048 / 4 / 256, 256, 0, stream>>>(x, xb, BS * 2048 / 4);
  k_transpose_bf16<<<dim3(2048 / 32, 512 / 32), 256, 0, stream>>>(wq_a_w, wfused, 2048, 512);
  k_transpose_bf16<<<dim3(2048 / 32, 576 / 32), 256, 0, stream>>>(
      wkv_a_w, wfused + (size_t)512 * 2048, 2048, 576);
  k_transpose_bf16<<<dim3(512 / 32, 3072 / 32), 256, 0, stream>>>(wq_b_w, wqbt, 512, 3072);
  k_transpose_bf16<<<dim3(512 / 32, 4096 / 32), 256, 0, stream>>>(wkv_b_w, wkvbt, 512, 4096);
  k_transpose_bf16<<<dim3(2048 / 32, 2048 / 32), 256, 0, stream>>>(wo_w, wot, 2048, 2048);
  k_rope_table<<<2048 * 32 / 256, 256, 0, stream>>>(cs);
  hipMemcpyAsync(biasf, wq_a_b, 512 * sizeof(float), hipMemcpyDeviceToDevice, stream);
  hipMemcpyAsync(biasf + 512, wkv_a_b, 576 * sizeof(float), hipMemcpyDeviceToDevice, stream);

  // fused GEMM1+GEMM3: qa (N=512) and ckv (N=576) in one pass over xb
  k_gemm_qkv<<<dim3(BS / 128, 9), 256, 0, stream>>>(xb, wfused, biasf, qa, ckv);
  // GEMM2: q = q_a @ wq_b + b
  k_gemm<unsigned short><<<dim3(BS / 128, 3072 / 128), 256, 0, stream>>>(
      qa, 512, wqbt, wq_b_b, qbuf, BS, 3072, 512);
  // RoPE in place
  k_rope_q<<<BS * 16 * 32 / 256, 256, 0, stream>>>(qbuf, cs);
  k_rope_k<<<BS * 32 / 256, 256, 0, stream>>>(ckv, cs);
  // GEMM4: kv = compressed_kv @ wkv_b + b
  k_gemm<unsigned short><<<dim3(BS / 128, 4096 / 128), 256, 0, stream>>>(
      ckv, 576, wkvbt, wkv_b_b, kvbuf, BS, 4096, 512);
  // attention: 256 blocks x 512 threads (1 block/CU, single pass)
  k_attn<<<2 * 16 * 8, 512, 0, stream>>>(qbuf, ckv, kvbuf, attno);
  // GEMM5: final projection, fp32 out
  k_gemm<float><<<dim3(BS / 128, 2048 / 128), 256, 0, stream>>>(
      attno, 2048, wot, wo_b, out, BS, 2048, 2048);
}